// Round 12
// baseline (280.747 us; speedup 1.0000x reference)
//
#include <hip/hip_runtime.h>

// ---------------------------------------------------------------------------
// UpsampleLayer: out = Upsample2x_FIR( W @ x ) + bias.  GEMM at 64x64 (commute)
// then FIR upsample to 127x127.
// Upsample math (validated R0-R10):
//   col j (even, j=2a): g = 1*z[a-1] + 3*z[a];  (odd, j=2a+1): g = 3*z[a]+z[a+1]
//   j==0: left tap 0.  Output row r: m=(r+1)>>1, rows (m-1, m), taps odd r ->
//   (3,1), even r -> (1,3), r=0 -> (0,3).  All *1/16 + bias.
//
// R9/R10 verdict: upsample NOT latency-bound (4x waves changed nothing) and
// not VALU-bound (12%). Write BW pinned at ~3.2 TB/s vs fillBuffer's 6.9 on
// the same buffer -> DRAM page locality: per-image wave streams scatter the
// active write window over ~64MB. R11: fillBuffer-style GRID-STRIDED ROW
// SWEEP -- all active half-waves write consecutive output rows, ~8MB window
// sweeping the 528MB buffer in address order. No carry (rows independent).
// ---------------------------------------------------------------------------

#define B_   16
#define CIN  512
#define COUT 512
#define S_   4096   // 64*64
#define HO   127
#define WO   127

typedef unsigned int  u32;
typedef unsigned short u16;
typedef __attribute__((ext_vector_type(8))) short  bf16x8;
typedef __attribute__((ext_vector_type(8))) u16    u16x8;
typedef __attribute__((ext_vector_type(4))) float  f32x4;

static __device__ __forceinline__ u16 f2bf(float f) {
  u32 u = __float_as_uint(f);
  u += 0x7FFFu + ((u >> 16) & 1u);   // RNE (inputs finite)
  return (u16)(u >> 16);
}
static __device__ __forceinline__ float bf2f(u16 h) {
  return __uint_as_float(((u32)h) << 16);
}

#if defined(__has_builtin)
#if __has_builtin(__builtin_amdgcn_global_load_lds)
#define HAS_GLOAD 1
#endif
#endif
#ifndef HAS_GLOAD
#define HAS_GLOAD 0
#endif

#if HAS_GLOAD
static __device__ __forceinline__ void gload16(const char* g, char* l) {
  __builtin_amdgcn_global_load_lds(
      (const __attribute__((address_space(1))) unsigned int*)g,
      (__attribute__((address_space(3))) unsigned int*)l, 16, 0, 0);
}
#endif

// ---------------------------------------------------------------------------
// Tiled operand layout (wt, xt), per 128(row) x 32(k) tile = 8 KiB:
// unit u = kg*128 + r holds 8 bf16, k = tk*32 + kg*8 + e.
// ---------------------------------------------------------------------------

__global__ __launch_bounds__(256) void conv_w_kernel(
    const float* __restrict__ w, u16* __restrict__ wt) {
  int g = blockIdx.x * 256 + threadIdx.x;
  int t_idx = g >> 9;
  int u = g & 511;
  int to = t_idx >> 4, tk = t_idx & 15;
  int r = u & 127, kg = u >> 7;
  int o = to * 128 + r;
  int c = tk * 32 + kg * 8;
  const float4* src = reinterpret_cast<const float4*>(w + (size_t)o * CIN + c);
  float4 lo = src[0], hi = src[1];
  u16x8 pk;
  pk[0] = f2bf(lo.x); pk[1] = f2bf(lo.y); pk[2] = f2bf(lo.z); pk[3] = f2bf(lo.w);
  pk[4] = f2bf(hi.x); pk[5] = f2bf(hi.y); pk[6] = f2bf(hi.z); pk[7] = f2bf(hi.w);
  *reinterpret_cast<u16x8*>(wt + (size_t)g * 8) = pk;
}

__global__ __launch_bounds__(256) void conv_x_kernel(
    const float* __restrict__ x, u16* __restrict__ xt) {
  int ts = blockIdx.x, tk = blockIdx.y, b = blockIdx.z;
  int t = threadIdx.x;
  __shared__ float lf[32 * 128];
  const float* src = x + ((size_t)(b * CIN + tk * 32)) * S_ + ts * 128;
#pragma unroll
  for (int i = 0; i < 4; ++i) {
    int q = i * 256 + t;
    int c = q >> 5, sq = q & 31;
    *reinterpret_cast<float4*>(&lf[c * 128 + sq * 4]) =
        *reinterpret_cast<const float4*>(src + (size_t)c * S_ + sq * 4);
  }
  __syncthreads();
  size_t tile_base = (((size_t)(b * 32 + ts)) * 16 + tk) * 512;
#pragma unroll
  for (int i = 0; i < 2; ++i) {
    int u = i * 256 + t;
    int kg = u >> 7, r = u & 127;
    u16x8 pk;
#pragma unroll
    for (int e = 0; e < 8; ++e) pk[e] = f2bf(lf[(kg * 8 + e) * 128 + r]);
    *reinterpret_cast<u16x8*>(xt + (tile_base + u) * 8) = pk;
  }
}

// GEMM (R4 exact): 128x128 tile, BK=32, 4 waves, mfma_f32_16x16x32_bf16.
__global__ __launch_bounds__(256) void gemm_kernel(
    const u16* __restrict__ wt, const u16* __restrict__ xt,
    u16* __restrict__ z) {
  int nt = blockIdx.x, mt = blockIdx.y, b = blockIdx.z;
  int t = threadIdx.x;
  __shared__ short lds[8192];
  char* lA = (char*)&lds[0];
  char* lB = lA + 8192;

  int lane = t & 63, wid = t >> 6;
  int wr = wid >> 1, wc = wid & 1;
  int lr = lane & 15, kg = lane >> 4;

  f32x4 acc[4][4];
#pragma unroll
  for (int m = 0; m < 4; ++m)
#pragma unroll
    for (int n = 0; n < 4; ++n) acc[m][n] = f32x4{0.f, 0.f, 0.f, 0.f};

  const char* gA = (const char*)wt + (size_t)(mt * 16) * 8192;
  const char* gB = (const char*)xt + ((size_t)(b * 32 + nt)) * 16 * 8192;

  int abyte[4], bbyte[4];
#pragma unroll
  for (int m = 0; m < 4; ++m) abyte[m] = (kg * 128 + wr * 64 + m * 16 + lr) * 16;
#pragma unroll
  for (int n = 0; n < 4; ++n) bbyte[n] = (kg * 128 + wc * 64 + n * 16 + lr) * 16;

  for (int ks = 0; ks < 16; ++ks) {
    const char* pA = gA + (size_t)ks * 8192;
    const char* pB = gB + (size_t)ks * 8192;
#if HAS_GLOAD
    __syncthreads();
    gload16(pA + t * 16, lA + t * 16);
    gload16(pA + 4096 + t * 16, lA + 4096 + t * 16);
    gload16(pB + t * 16, lB + t * 16);
    gload16(pB + 4096 + t * 16, lB + 4096 + t * 16);
    __syncthreads();
#else
    u16x8 va0 = *reinterpret_cast<const u16x8*>(pA + t * 16);
    u16x8 va1 = *reinterpret_cast<const u16x8*>(pA + 4096 + t * 16);
    u16x8 vb0 = *reinterpret_cast<const u16x8*>(pB + t * 16);
    u16x8 vb1 = *reinterpret_cast<const u16x8*>(pB + 4096 + t * 16);
    __syncthreads();
    *reinterpret_cast<u16x8*>(lA + t * 16) = va0;
    *reinterpret_cast<u16x8*>(lA + 4096 + t * 16) = va1;
    *reinterpret_cast<u16x8*>(lB + t * 16) = vb0;
    *reinterpret_cast<u16x8*>(lB + 4096 + t * 16) = vb1;
    __syncthreads();
#endif
    bf16x8 av[4], bv[4];
#pragma unroll
    for (int m = 0; m < 4; ++m)
      av[m] = *reinterpret_cast<const bf16x8*>(lA + abyte[m]);
#pragma unroll
    for (int n = 0; n < 4; ++n)
      bv[n] = *reinterpret_cast<const bf16x8*>(lB + bbyte[n]);
#pragma unroll
    for (int m = 0; m < 4; ++m)
#pragma unroll
      for (int n = 0; n < 4; ++n)
        acc[m][n] = __builtin_amdgcn_mfma_f32_16x16x32_bf16(
            av[m], bv[n], acc[m][n], 0, 0, 0);
  }

  int o_b = mt * 128 + wr * 64 + kg * 4;
  int s_b = nt * 128 + wc * 64 + lr;
#pragma unroll
  for (int m = 0; m < 4; ++m)
#pragma unroll
    for (int n = 0; n < 4; ++n) {
      f32x4 v = acc[m][n];
      size_t base = ((size_t)(b * COUT + o_b + m * 16)) * S_ + (s_b + n * 16);
#pragma unroll
      for (int r = 0; r < 4; ++r) z[base + (size_t)r * S_] = f2bf(v[r]);
    }
}

// R11 upsample: grid-strided ROW SWEEP. Half-wave (32 lanes) h handles output
// rows r_glob = h, h+H, ... in ascending global address order -> all active
// writes stay in a narrow window sweeping the output buffer (DRAM page
// locality, fillBuffer-style). Row r of image img: m=(r+1)>>1, z rows
// (m-1, m), taps odd r (3,1) / even r (1,3) / r==0 (0,3). Lane l owns out
// cols 4l..4l+3 from z dwords P/C/N (cols 2l-2..2l+3). No inter-row carry.
__global__ __launch_bounds__(256) void upsample_kernel(
    const u16* __restrict__ z, const float* __restrict__ bias,
    float* __restrict__ out) {
  const u32 TOT = (u32)B_ * COUT * HO;  // 1,040,384 rows
  u32 H = gridDim.x * 8u;               // half-waves in grid
  u32 hid = blockIdx.x * 8u + (threadIdx.x >> 5);
  int l = threadIdx.x & 31;
  int lp = (l == 0) ? 0 : l - 1;
  int ln = (l == 31) ? 31 : l + 1;
  float tA0 = (l == 0) ? 0.f : 1.f;   // col-0 left tap mask
  bool full = (l < 31);

  for (u32 rg = hid; rg < TOT; rg += H) {
    u32 img = rg / 127u;              // compiler magic-mul
    u32 r = rg - img * 127u;
    const u32* zi = reinterpret_cast<const u32*>(z) + ((size_t)img << 11);
    float bv = bias[img & 511u];

    u32 m = (r + 1) >> 1;
    int a = (int)m - 1;
    float wa = (r & 1) ? 3.f : 1.f;   // tap on z row m-1
    float wb = (r & 1) ? 1.f : 3.f;   // tap on z row m
    if (a < 0) { a = 0; wa = 0.f; }   // r==0

    const u32* rA = zi + a * 32;
    const u32* rB = zi + (int)m * 32;
    u32 Pa = rA[lp], Ca = rA[l], Na = rA[ln];
    u32 Pb = rB[lp], Cb = rB[l], Nb = rB[ln];

    float a0 = bf2f((u16)Ca), a1 = bf2f((u16)(Ca >> 16));
    float aP = bf2f((u16)(Pa >> 16)), aN = bf2f((u16)Na);
    float gA0 = fmaf(3.f, a0, tA0 * aP);   // col 4l
    float gA1 = fmaf(3.f, a0, a1);         // col 4l+1
    float gA2 = fmaf(3.f, a1, a0);         // col 4l+2
    float gA3 = fmaf(3.f, a1, aN);         // col 4l+3

    float b0 = bf2f((u16)Cb), b1 = bf2f((u16)(Cb >> 16));
    float bP = bf2f((u16)(Pb >> 16)), bN = bf2f((u16)Nb);
    float gB0 = fmaf(3.f, b0, tA0 * bP);
    float gB1 = fmaf(3.f, b0, b1);
    float gB2 = fmaf(3.f, b1, b0);
    float gB3 = fmaf(3.f, b1, bN);

    float v0 = fmaf(fmaf(wa, gA0, wb * gB0), 0.0625f, bv);
    float v1 = fmaf(fmaf(wa, gA1, wb * gB1), 0.0625f, bv);
    float v2 = fmaf(fmaf(wa, gA2, wb * gB2), 0.0625f, bv);
    float v3 = fmaf(fmaf(wa, gA3, wb * gB3), 0.0625f, bv);

    float* po = out + (size_t)rg * WO + 4 * l;  // rows are globally contiguous
    if (full) {
      float vv[4] = {v0, v1, v2, v3};
      __builtin_memcpy(po, vv, 16);
    } else {  // cols 124..126 (127 dropped)
      po[0] = v0; po[1] = v1; po[2] = v2;
    }
  }
}

// Fallback (no workspace).
__global__ __launch_bounds__(256) void fallback_kernel(
    const float* __restrict__ x, const float* __restrict__ w,
    const float* __restrict__ bias, float* __restrict__ out) {
  u32 idx = blockIdx.x * 256u + threadIdx.x;
  const u32 total = (u32)B_ * COUT * HO * WO;
  if (idx >= total) return;
  u32 j = idx % WO;
  u32 r1 = idx / WO;
  u32 i = r1 % HO;
  u32 bo = r1 / HO;
  int o = (int)(bo & 511u);
  int b = (int)(bo >> 9);
  int m = (int)(i >> 1), n = (int)(j >> 1);
  int ie = !(i & 1), je = !(j & 1);
  int rA = ie ? m - 1 : m;
  int cA = je ? n - 1 : n;
  float w_r0 = ie ? 1.f : 3.f, w_r1 = ie ? 3.f : 1.f;
  float w_c0 = je ? 1.f : 3.f, w_c1 = je ? 3.f : 1.f;
  const float* xb = x + (size_t)b * CIN * S_;
  float acc = 0.f;
  for (int cc = 0; cc < CIN; ++cc) {
    const float* xc = xb + (size_t)cc * S_;
    float y = 0.f;
    if (rA >= 0) {
      if (cA >= 0) y += w_r0 * w_c0 * xc[rA * 64 + cA];
      y += w_r0 * w_c1 * xc[rA * 64 + cA + 1];
    }
    if (cA >= 0) y += w_r1 * w_c0 * xc[(rA + 1) * 64 + cA];
    y += w_r1 * w_c1 * xc[(rA + 1) * 64 + cA + 1];
    acc += y * w[(size_t)o * CIN + cc];
  }
  out[idx] = acc * 0.0625f + bias[o];
}

extern "C" void kernel_launch(void* const* d_in, const int* in_sizes, int n_in,
                              void* d_out, int out_size, void* d_ws,
                              size_t ws_size, hipStream_t stream) {
  const float* x = (const float*)d_in[0];
  const float* w = (const float*)d_in[2];
  const float* bias = (const float*)d_in[3];
  float* out = (float*)d_out;

  const size_t xt_bytes = (size_t)B_ * S_ * CIN * 2;       // 64 MiB
  const size_t wt_off = xt_bytes;
  const size_t wt_bytes = (size_t)COUT * CIN * 2;          // 512 KiB
  const size_t z_off = wt_off + ((wt_bytes + 255) & ~(size_t)255);
  const size_t need = z_off + (size_t)B_ * COUT * S_ * 2;
  const size_t total_out = (size_t)B_ * COUT * HO * WO;
  const u32 nblk_out = (u32)((total_out + 255) / 256);

  if (ws_size >= need) {
    u16* xt = (u16*)d_ws;
    u16* wt = (u16*)((char*)d_ws + wt_off);
    u16* zz = (u16*)((char*)d_ws + z_off);
    conv_w_kernel<<<128, 256, 0, stream>>>(w, wt);
    conv_x_kernel<<<dim3(32, 16, B_), 256, 0, stream>>>(x, xt);
    gemm_kernel<<<dim3(32, 4, B_), 256, 0, stream>>>(wt, xt, zz);
    // Grid-strided row sweep: 2048 blocks = 16384 half-waves.
    upsample_kernel<<<2048, 256, 0, stream>>>(zz, bias, out);
  } else {
    fallback_kernel<<<nblk_out, 256, 0, stream>>>(x, w, bias, out);
  }
}